// Round 5
// baseline (326.124 us; speedup 1.0000x reference)
//
#include <hip/hip_runtime.h>
#include <math.h>

// CausalSemanticGrouping: key [B,N,D] fp32, slot_embed [K,D] fp32
#define BB 64
#define NN 1024
#define DD 512
#define KK 64
#define CC 1088   // K + N

// d_out: out [B,K,D] fp32 then dots [B,K,C] fp32.
// d_ws (floats): rslot [0,64) | rkey [64, 64+B*N) | attn [64+B*N, +B*K*C)
//   = 17.25 MiB, identical to the R1/R3 PASSING layout. No bf16 tensors in ws
//   (the bf16-relay pattern failed identically in R2 and R4 — banned).

typedef __bf16 bf16_t;
typedef __bf16 bf16x4 __attribute__((ext_vector_type(4)));
typedef __bf16 bf16x8 __attribute__((ext_vector_type(8)));
typedef float f32x16 __attribute__((ext_vector_type(16)));

__device__ __forceinline__ float waveReduceSum(float v) {
    #pragma unroll
    for (int off = 32; off > 0; off >>= 1) v += __shfl_down(v, off, 64);
    return v;
}
__device__ __forceinline__ float waveReduceMax(float v) {
    #pragma unroll
    for (int off = 32; off > 0; off >>= 1) v = fmaxf(v, __shfl_down(v, off, 64));
    return v;
}
// split x into bf16 hi + bf16 lo, x ~= hi + lo (~2^-16 relative error)
__device__ __forceinline__ void split4(float4 x, bf16x4& hi, bf16x4& lo) {
    float v[4] = {x.x, x.y, x.z, x.w};
    #pragma unroll
    for (int j = 0; j < 4; j++) {
        __bf16 h = (__bf16)v[j];
        hi[j] = h;
        lo[j] = (__bf16)(v[j] - (float)h);
    }
}
__device__ __forceinline__ void split8(float4 x0, float4 x1, bf16x8& hi, bf16x8& lo) {
    bf16x4 h0, l0, h1, l1;
    split4(x0, h0, l0);
    split4(x1, h1, l1);
    #pragma unroll
    for (int j = 0; j < 4; j++) {
        hi[j] = h0[j];  hi[j + 4] = h1[j];
        lo[j] = l0[j];  lo[j + 4] = l1[j];
    }
}

// 1 / max(||slot_k||, 1e-12). grid: K x 64 (1 wave/row)
__global__ __launch_bounds__(64) void k_rslot(const float* __restrict__ slot,
                                              float* __restrict__ rslot) {
    int k = blockIdx.x, lane = threadIdx.x;
    const float* row = slot + (size_t)k * DD;
    float s = 0.f;
    #pragma unroll
    for (int i = 0; i < DD / 64; i++) { float v = row[lane + i * 64]; s += v * v; }
    s = waveReduceSum(s);
    if (lane == 0) rslot[k] = 1.0f / fmaxf(sqrtf(s), 1e-12f);
}

// 1 / max(||key_bn||, 1e-12). grid: B*N/4 x 256 (1 wave/row)
__global__ __launch_bounds__(256) void k_rkey(const float* __restrict__ key,
                                              float* __restrict__ rkey) {
    int wave = threadIdx.x >> 6, lane = threadIdx.x & 63;
    size_t row = (size_t)blockIdx.x * 4 + wave;
    const float4* p = (const float4*)(key + row * DD);
    float4 a = p[lane], b = p[lane + 64];
    float s = a.x*a.x + a.y*a.y + a.z*a.z + a.w*a.w
            + b.x*b.x + b.y*b.y + b.z*b.z + b.w*b.w;
    s = waveReduceSum(s);
    if (lane == 0) rkey[row] = 1.0f / fmaxf(sqrtf(s), 1e-12f);
}

// dots[b, 0:64, c0:+64]: zero-LDS, barrier-free split-bf16 MFMA GEMM.
// Fragments loaded directly from fp32 global (d_in), split in registers.
// grid (17, B) x 256 (4 waves; wave w -> 32x32 subtile (mw, nw)).
__global__ __launch_bounds__(256) void k_dots(const float* __restrict__ key,
                                              const float* __restrict__ slot,
                                              const float* __restrict__ rslot,
                                              const float* __restrict__ rkey,
                                              float* __restrict__ dots) {
    const int b = blockIdx.y, c0 = blockIdx.x * 64;
    const int tid = threadIdx.x;
    const int w = tid >> 6, lane = tid & 63;
    const int mw = (w >> 1) * 32, nw = (w & 1) * 32;
    const int m = mw + (lane & 31);
    const int c = c0 + nw + (lane & 31);
    const int half = (lane >> 5) * 8;   // which 8-wide k-slice of the 16-step

    const float* ap = slot + (size_t)m * DD + half;
    const float* bp = (c < KK) ? slot + (size_t)c * DD + half
                               : key + ((size_t)b * NN + (c - KK)) * DD + half;

    f32x16 acc = {};
    #pragma unroll 4
    for (int kk = 0; kk < DD; kk += 16) {
        float4 a0 = *(const float4*)(ap + kk);
        float4 a1 = *(const float4*)(ap + kk + 4);
        float4 b0 = *(const float4*)(bp + kk);
        float4 b1 = *(const float4*)(bp + kk + 4);
        bf16x8 ah, al, bh, bl;
        split8(a0, a1, ah, al);
        split8(b0, b1, bh, bl);
        acc = __builtin_amdgcn_mfma_f32_32x32x16_bf16(ah, bh, acc, 0, 0, 0);
        acc = __builtin_amdgcn_mfma_f32_32x32x16_bf16(ah, bl, acc, 0, 0, 0);
        acc = __builtin_amdgcn_mfma_f32_32x32x16_bf16(al, bh, acc, 0, 0, 0);
    }

    const float rn = (c < KK) ? rslot[c] : rkey[(size_t)b * NN + (c - KK)];
    #pragma unroll
    for (int reg = 0; reg < 16; reg++) {
        int mr = mw + (reg & 3) + 8 * (reg >> 2) + 4 * (lane >> 5);
        dots[((size_t)b * KK + mr) * CC + c] = acc[reg] * rslot[mr] * rn;
    }
}

// masked softmax(dots/TEMP), /(1+1e-7), fp32 attn in ws. grid (K, B) x 256.
__global__ __launch_bounds__(256) void k_softmax(const float* __restrict__ dots,
                                                 float* __restrict__ attn) {
    const int k = blockIdx.x, b = blockIdx.y;
    const float* row = dots + ((size_t)b * KK + k) * CC;
    float* arow = attn + ((size_t)b * KK + k) * CC;
    const int tid = threadIdx.x;
    __shared__ float red[4];

    float vals[5];
    int cnt = 0;
    float m = -INFINITY;
    for (int c = tid; c < CC; c += 256) {
        bool ok = (c >= KK) || (c < k);   // strict lower-tri slot-slot, all keys
        float x = ok ? (row[c] / 0.07f) : -INFINITY;
        vals[cnt++] = x;
        m = fmaxf(m, x);
    }
    m = waveReduceMax(m);
    if ((tid & 63) == 0) red[tid >> 6] = m;
    __syncthreads();
    m = fmaxf(fmaxf(red[0], red[1]), fmaxf(red[2], red[3]));

    float s = 0.f;
    cnt = 0;
    for (int c = tid; c < CC; c += 256) {
        float e = (vals[cnt] == -INFINITY) ? 0.0f : expf(vals[cnt] - m);
        vals[cnt] = e;
        s += e;
        cnt++;
    }
    s = waveReduceSum(s);
    __syncthreads();
    if ((tid & 63) == 0) red[tid >> 6] = s;
    __syncthreads();
    s = red[0] + red[1] + red[2] + red[3];

    float inv = 1.0f / (s * (1.0f + 1e-7f));
    cnt = 0;
    for (int c = tid; c < CC; c += 256) arow[c] = vals[cnt++] * inv;
}

// out[b, 0:64, d0:+64] = attn (64xC) x V (CxD). A (attn, ws fp32) fragments
// direct from global + register split; V transposed via LDS (R3-proven code).
// grid (8, B) x 256.
__global__ __launch_bounds__(256) void k_out(const float* __restrict__ key,
                                             const float* __restrict__ slot,
                                             const float* __restrict__ attn,
                                             float* __restrict__ out) {
    __shared__ __align__(16) bf16_t Vhi[64][72], Vlo[64][72];   // [d][c]
    const int b = blockIdx.y, d0 = blockIdx.x * 64;
    const int tid = threadIdx.x;
    const int w = tid >> 6, lane = tid & 63;
    const int mw = (w >> 1) * 32, nw = (w & 1) * 32;
    const int cpair = tid & 31, dg = tid >> 5;    // staging roles for V
    const int m = mw + (lane & 31);
    const int half = (lane >> 5) * 8;
    const float* ap = attn + ((size_t)b * KK + m) * CC + half;

    f32x16 acc = {};
    for (int c0 = 0; c0 < CC; c0 += 64) {
        {   // stage V^T tile: thread owns rows (c, c+1), d-range d0+dg*8..+8
            int c = c0 + 2 * cpair;
            const float* r0 = (c < KK)     ? &slot[(size_t)c * DD]
                                           : &key[((size_t)b * NN + (c - KK)) * DD];
            const float* r1 = (c + 1 < KK) ? &slot[(size_t)(c + 1) * DD]
                                           : &key[((size_t)b * NN + (c + 1 - KK)) * DD];
            float4 v0a = *(const float4*)(r0 + d0 + dg * 8);
            float4 v0b = *(const float4*)(r0 + d0 + dg * 8 + 4);
            float4 v1a = *(const float4*)(r1 + d0 + dg * 8);
            float4 v1b = *(const float4*)(r1 + d0 + dg * 8 + 4);
            bf16x4 h0a, l0a, h0b, l0b, h1a, l1a, h1b, l1b;
            split4(v0a, h0a, l0a); split4(v0b, h0b, l0b);
            split4(v1a, h1a, l1a); split4(v1b, h1b, l1b);
            #pragma unroll
            for (int j = 0; j < 8; j++) {
                __bf16 h0 = (j < 4) ? h0a[j] : h0b[j - 4];
                __bf16 l0 = (j < 4) ? l0a[j] : l0b[j - 4];
                __bf16 h1 = (j < 4) ? h1a[j] : h1b[j - 4];
                __bf16 l1 = (j < 4) ? l1a[j] : l1b[j - 4];
                unsigned hw = (unsigned)__builtin_bit_cast(unsigned short, h0)
                            | ((unsigned)__builtin_bit_cast(unsigned short, h1) << 16);
                unsigned lw = (unsigned)__builtin_bit_cast(unsigned short, l0)
                            | ((unsigned)__builtin_bit_cast(unsigned short, l1) << 16);
                *(unsigned*)&Vhi[dg * 8 + j][2 * cpair] = hw;
                *(unsigned*)&Vlo[dg * 8 + j][2 * cpair] = lw;
            }
        }
        __syncthreads();
        #pragma unroll
        for (int kk2 = 0; kk2 < 64; kk2 += 16) {
            float4 a0 = *(const float4*)(ap + c0 + kk2);
            float4 a1 = *(const float4*)(ap + c0 + kk2 + 4);
            bf16x8 ah, al;
            split8(a0, a1, ah, al);
            bf16x8 vh = *(bf16x8*)&Vhi[nw + (lane & 31)][kk2 + half];
            bf16x8 vl = *(bf16x8*)&Vlo[nw + (lane & 31)][kk2 + half];
            acc = __builtin_amdgcn_mfma_f32_32x32x16_bf16(ah, vh, acc, 0, 0, 0);
            acc = __builtin_amdgcn_mfma_f32_32x32x16_bf16(ah, vl, acc, 0, 0, 0);
            acc = __builtin_amdgcn_mfma_f32_32x32x16_bf16(al, vh, acc, 0, 0, 0);
        }
        __syncthreads();
    }

    const int d = d0 + nw + (lane & 31);
    #pragma unroll
    for (int reg = 0; reg < 16; reg++) {
        int mr = mw + (reg & 3) + 8 * (reg >> 2) + 4 * (lane >> 5);
        out[((size_t)b * KK + mr) * DD + d] = acc[reg];
    }
}

extern "C" void kernel_launch(void* const* d_in, const int* in_sizes, int n_in,
                              void* d_out, int out_size, void* d_ws, size_t ws_size,
                              hipStream_t stream) {
    const float* key  = (const float*)d_in[0];   // [B, N, D]
    const float* slot = (const float*)d_in[1];   // [K, D]
    float* out  = (float*)d_out;                        // [B, K, D]
    float* dots = out + (size_t)BB * KK * DD;           // [B, K, C]
    float* ws = (float*)d_ws;
    float* rslot = ws;                                  // [K]
    float* rkey  = ws + 64;                             // [B*N]
    float* attn  = ws + 64 + (size_t)BB * NN;           // [B, K, C] fp32

    k_rslot<<<dim3(KK), dim3(64), 0, stream>>>(slot, rslot);
    k_rkey<<<dim3(BB * NN / 4), dim3(256), 0, stream>>>(key, rkey);
    k_dots<<<dim3(CC / 64, BB), dim3(256), 0, stream>>>(key, slot, rslot, rkey, dots);
    k_softmax<<<dim3(KK, BB), dim3(256), 0, stream>>>(dots, attn);
    k_out<<<dim3(DD / 64, BB), dim3(256), 0, stream>>>(key, slot, attn, out);
}